// Round 4
// baseline (195.521 us; speedup 1.0000x reference)
//
#include <hip/hip_runtime.h>
#include <hip/hip_bf16.h>
#include <stdint.h>

#define D_DIM 1024
#define B_DIM 8
#define S_DIM 1024

typedef __bf16 bf16;
typedef __bf16 bf16x4 __attribute__((ext_vector_type(4)));
typedef __bf16 bf16x8 __attribute__((ext_vector_type(8)));
typedef float floatx4 __attribute__((ext_vector_type(4)));

// ---------------------------------------------------------------------------
// Fully fused 2-kernel chain (prep eliminated):
//   K1: tmpD[b,j,d] = sum_k dep[b,j,k] * U[d,k]   (fp32 in, bf16 out)
//       + fused s_dep[b,j] = dep[b,j,:] . w2      (bx==0 blocks)
//   K2: out[b,i,j]  = sum_d head[b,i,d] * tmpD[b,j,d]
//                     + s_head[i] + s_dep[j] + bias
//       s_head computed IN-KERNEL from the fp32 head rows each block
//       already stages (never materialized to HBM).
// Both GEMMs: 128x128 tile, BK=64, 512 thr (8 waves 2Mx4N, per-wave 64x32,
// acc[4][2]) — the verified R1 structure. Staging is reg-based (fp32 load ->
// cvt -> swizzled ds_write), loads issued ONE TILE EARLY so HBM latency
// hides under the previous tile's MFMA. LDS read side / XOR swizzle /
// epilogue mapping identical to the R1 kernel (known conflict-free).
// Traffic: 200 MB (3-kernel chain) -> ~134 MB, one launch gap removed.
// ---------------------------------------------------------------------------

__device__ __forceinline__ bf16x4 cvt4(float4 v) {
    bf16x4 o;
    o[0] = (bf16)v.x; o[1] = (bf16)v.y; o[2] = (bf16)v.z; o[3] = (bf16)v.w;
    return o;
}

// A-side thread mapping (fp32 staging, 128 rows x 64 cols per tile):
// it in [0,4): idx = it*512 + tid; row = idx>>4; col = (idx&15)*4.
// 16 consecutive tids cover one row's 64 floats (256 B contiguous).
// LDS dest (bf16 granules of 8, XOR-swizzled): granule gg = c16>>1,
// half = c16&1, elem off = row*64 + (gg ^ (row&7))*8 + half*4.

// B-side bf16 staging (K2): jt in [0,2): idx = jt*512 + tid; row = idx>>3;
// gB = idx&7; 8 tids cover one row's 64 bf16 (128 B contiguous).

// ---------------------------------------------------------------------------
// K1: A = dep fp32 [8192 x 1024], B = U fp32 [1024 x 1024] (row-major = Bt),
//     C = tmpD bf16. Grid 8 x 64 = 512 blocks.
// ---------------------------------------------------------------------------
__global__ __launch_bounds__(512) void gemm1_kernel(
    const float* __restrict__ dep, const float* __restrict__ U,
    const float* __restrict__ edge_W,
    bf16* __restrict__ tmpD, float* __restrict__ s_dep)
{
    __shared__ bf16 As[128 * 64];
    __shared__ bf16 Bs[128 * 64];

    int tid  = threadIdx.x;
    int wid  = tid >> 6;
    int lane = tid & 63;
    int quad = lane >> 4;
    int l16  = lane & 15;
    int wr   = wid >> 2;   // 0..1
    int wc   = wid & 3;    // 0..3

    // XCD-chunk swizzle (nwg = 512, bijective)
    int nx  = gridDim.x, ny = gridDim.y;
    int lin = blockIdx.x + nx * blockIdx.y;
    int nwg = nx * ny;
    int swz = (lin & 7) * (nwg >> 3) + (lin >> 3);
    int bx  = swz % nx;
    int by  = swz / nx;

    int tile_m = by * 128;   // dep rows (flattened b*S+j)
    int tile_n = bx * 128;   // U rows (d)
    const float* Ab = dep + (size_t)tile_m * D_DIM;
    const float* Bb = U   + (size_t)tile_n * D_DIM;
    const float* w2 = edge_W + D_DIM;
    bool do_proj = (bx == 0);

    int rA[4], cA[4];
    #pragma unroll
    for (int it = 0; it < 4; ++it) {
        int idx = it * 512 + tid;
        rA[it] = idx >> 4;
        cA[it] = (idx & 15) * 4;
    }

    floatx4 zero = {0.0f, 0.0f, 0.0f, 0.0f};
    floatx4 acc[4][2];
    #pragma unroll
    for (int i = 0; i < 4; ++i)
        #pragma unroll
        for (int j = 0; j < 2; ++j) acc[i][j] = zero;
    float proj[4] = {0.f, 0.f, 0.f, 0.f};

    float4 va[4], vb[4], vw[4];
    #pragma unroll
    for (int it = 0; it < 4; ++it) {
        va[it] = *(const float4*)&Ab[(size_t)rA[it] * D_DIM + cA[it]];
        vb[it] = *(const float4*)&Bb[(size_t)rA[it] * D_DIM + cA[it]];
    }
    if (do_proj) {
        #pragma unroll
        for (int it = 0; it < 4; ++it)
            vw[it] = *(const float4*)&w2[cA[it]];
    }

    const int NT = D_DIM / 64;   // 16
    for (int t = 0; t < NT; ++t) {
        __syncthreads();   // all waves done reading previous tile
        #pragma unroll
        for (int it = 0; it < 4; ++it) {
            int r   = rA[it];
            int c16 = cA[it] >> 2;
            int gg  = c16 >> 1, half = c16 & 1;
            int off = r * 64 + ((gg ^ (r & 7)) * 8) + half * 4;
            *(bf16x4*)&As[off] = cvt4(va[it]);
            *(bf16x4*)&Bs[off] = cvt4(vb[it]);
            if (do_proj)
                proj[it] += va[it].x * vw[it].x + va[it].y * vw[it].y
                          + va[it].z * vw[it].z + va[it].w * vw[it].w;
        }
        if (t + 1 < NT) {   // early-issue next tile (hides under MFMA below)
            int k0 = (t + 1) * 64;
            #pragma unroll
            for (int it = 0; it < 4; ++it) {
                va[it] = *(const float4*)&Ab[(size_t)rA[it] * D_DIM + k0 + cA[it]];
                vb[it] = *(const float4*)&Bb[(size_t)rA[it] * D_DIM + k0 + cA[it]];
            }
            if (do_proj) {
                #pragma unroll
                for (int it = 0; it < 4; ++it)
                    vw[it] = *(const float4*)&w2[k0 + cA[it]];
            }
        }
        __syncthreads();   // tile staged

        #pragma unroll
        for (int kk = 0; kk < 64; kk += 32) {
            bf16x8 a[4], b[2];
            #pragma unroll
            for (int mt = 0; mt < 4; ++mt) {
                int row  = wr * 64 + mt * 16 + l16;
                int slot = ((kk >> 3) + quad) ^ (row & 7);
                a[mt] = *(const bf16x8*)&As[row * 64 + slot * 8];
            }
            #pragma unroll
            for (int nt = 0; nt < 2; ++nt) {
                int row  = wc * 32 + nt * 16 + l16;
                int slot = ((kk >> 3) + quad) ^ (row & 7);
                b[nt] = *(const bf16x8*)&Bs[row * 64 + slot * 8];
            }
            __builtin_amdgcn_s_setprio(1);
            #pragma unroll
            for (int mt = 0; mt < 4; ++mt)
                #pragma unroll
                for (int nt = 0; nt < 2; ++nt)
                    acc[mt][nt] = __builtin_amdgcn_mfma_f32_16x16x32_bf16(
                        a[mt], b[nt], acc[mt][nt], 0, 0, 0);
            __builtin_amdgcn_s_setprio(0);
        }
    }

    // fused s_dep write (row rA[it] handled by 16 consecutive lanes)
    if (do_proj) {
        #pragma unroll
        for (int it = 0; it < 4; ++it) {
            float v = proj[it];
            v += __shfl_xor(v, 1, 16);
            v += __shfl_xor(v, 2, 16);
            v += __shfl_xor(v, 4, 16);
            v += __shfl_xor(v, 8, 16);
            if ((tid & 15) == 0) s_dep[tile_m + rA[it]] = v;
        }
    }

    // epilogue: C/D layout col = lane&15, row = quad*4 + reg
    int row0 = tile_m + wr * 64;
    int col0 = tile_n + wc * 32;
    #pragma unroll
    for (int mt = 0; mt < 4; ++mt)
        #pragma unroll
        for (int r = 0; r < 4; ++r) {
            int row = row0 + mt * 16 + quad * 4 + r;
            #pragma unroll
            for (int nt = 0; nt < 2; ++nt) {
                int col = col0 + nt * 16 + l16;
                tmpD[(size_t)row * D_DIM + col] = (bf16)acc[mt][nt][r];
            }
        }
}

// ---------------------------------------------------------------------------
// K2: A = head fp32 (batched), B = tmpD bf16 (batched), C = out fp32.
//     Grid 8 x 8 x 8 = 512 blocks. s_head computed in-kernel into LDS.
// ---------------------------------------------------------------------------
__global__ __launch_bounds__(512) void gemm2_kernel(
    const float* __restrict__ head, const bf16* __restrict__ tmpD,
    const float* __restrict__ edge_W, const float* __restrict__ s_dep,
    const float* __restrict__ edge_b, float* __restrict__ out)
{
    __shared__ bf16 As[128 * 64];
    __shared__ bf16 Bs[128 * 64];
    __shared__ float smrow[128];

    int tid  = threadIdx.x;
    int wid  = tid >> 6;
    int lane = tid & 63;
    int quad = lane >> 4;
    int l16  = lane & 15;
    int wr   = wid >> 2;   // 0..1
    int wc   = wid & 3;    // 0..3

    int nx  = gridDim.x, ny = gridDim.y;
    int lin = blockIdx.x + nx * (blockIdx.y + ny * blockIdx.z);
    int nwg = nx * ny * gridDim.z;     // 512
    int swz = (lin & 7) * (nwg >> 3) + (lin >> 3);
    int bx  = swz % nx;
    int rem = swz / nx;
    int by  = rem % ny;
    int bz  = rem / ny;

    int tile_m = by * 128;   // head rows i
    int tile_n = bx * 128;   // tmpD rows j
    const float* Ab = head + (size_t)bz * S_DIM * D_DIM + (size_t)tile_m * D_DIM;
    const bf16*  Bb = tmpD + (size_t)bz * S_DIM * D_DIM + (size_t)tile_n * D_DIM;
    const float* w1 = edge_W;

    int rA[4], cA[4];
    #pragma unroll
    for (int it = 0; it < 4; ++it) {
        int idx = it * 512 + tid;
        rA[it] = idx >> 4;
        cA[it] = (idx & 15) * 4;
    }
    int rB[2], gB[2];
    #pragma unroll
    for (int jt = 0; jt < 2; ++jt) {
        int idx = jt * 512 + tid;
        rB[jt] = idx >> 3;
        gB[jt] = idx & 7;
    }

    floatx4 zero = {0.0f, 0.0f, 0.0f, 0.0f};
    floatx4 acc[4][2];
    #pragma unroll
    for (int i = 0; i < 4; ++i)
        #pragma unroll
        for (int j = 0; j < 2; ++j) acc[i][j] = zero;
    float proj[4] = {0.f, 0.f, 0.f, 0.f};

    float4 va[4], vw[4];
    bf16x8 pb[2];
    #pragma unroll
    for (int it = 0; it < 4; ++it) {
        va[it] = *(const float4*)&Ab[(size_t)rA[it] * D_DIM + cA[it]];
        vw[it] = *(const float4*)&w1[cA[it]];
    }
    #pragma unroll
    for (int jt = 0; jt < 2; ++jt)
        pb[jt] = *(const bf16x8*)&Bb[(size_t)rB[jt] * D_DIM + gB[jt] * 8];

    const int NT = D_DIM / 64;   // 16
    for (int t = 0; t < NT; ++t) {
        __syncthreads();
        #pragma unroll
        for (int it = 0; it < 4; ++it) {
            int r   = rA[it];
            int c16 = cA[it] >> 2;
            int gg  = c16 >> 1, half = c16 & 1;
            int off = r * 64 + ((gg ^ (r & 7)) * 8) + half * 4;
            *(bf16x4*)&As[off] = cvt4(va[it]);
            proj[it] += va[it].x * vw[it].x + va[it].y * vw[it].y
                      + va[it].z * vw[it].z + va[it].w * vw[it].w;
        }
        #pragma unroll
        for (int jt = 0; jt < 2; ++jt) {
            int r = rB[jt];
            int off = r * 64 + ((gB[jt] ^ (r & 7)) * 8);
            *(bf16x8*)&Bs[off] = pb[jt];
        }
        if (t + 1 < NT) {
            int k0 = (t + 1) * 64;
            #pragma unroll
            for (int it = 0; it < 4; ++it) {
                va[it] = *(const float4*)&Ab[(size_t)rA[it] * D_DIM + k0 + cA[it]];
                vw[it] = *(const float4*)&w1[k0 + cA[it]];
            }
            #pragma unroll
            for (int jt = 0; jt < 2; ++jt)
                pb[jt] = *(const bf16x8*)&Bb[(size_t)rB[jt] * D_DIM + k0 + gB[jt] * 8];
        }
        __syncthreads();

        #pragma unroll
        for (int kk = 0; kk < 64; kk += 32) {
            bf16x8 a[4], b[2];
            #pragma unroll
            for (int mt = 0; mt < 4; ++mt) {
                int row  = wr * 64 + mt * 16 + l16;
                int slot = ((kk >> 3) + quad) ^ (row & 7);
                a[mt] = *(const bf16x8*)&As[row * 64 + slot * 8];
            }
            #pragma unroll
            for (int nt = 0; nt < 2; ++nt) {
                int row  = wc * 32 + nt * 16 + l16;
                int slot = ((kk >> 3) + quad) ^ (row & 7);
                b[nt] = *(const bf16x8*)&Bs[row * 64 + slot * 8];
            }
            __builtin_amdgcn_s_setprio(1);
            #pragma unroll
            for (int mt = 0; mt < 4; ++mt)
                #pragma unroll
                for (int nt = 0; nt < 2; ++nt)
                    acc[mt][nt] = __builtin_amdgcn_mfma_f32_16x16x32_bf16(
                        a[mt], b[nt], acc[mt][nt], 0, 0, 0);
            __builtin_amdgcn_s_setprio(0);
        }
    }

    // s_head: reduce per-row projections into LDS (local use only)
    #pragma unroll
    for (int it = 0; it < 4; ++it) {
        float v = proj[it];
        v += __shfl_xor(v, 1, 16);
        v += __shfl_xor(v, 2, 16);
        v += __shfl_xor(v, 4, 16);
        v += __shfl_xor(v, 8, 16);
        if ((tid & 15) == 0) smrow[rA[it]] = v;
    }
    __syncthreads();

    // epilogue: fp32 + s_head(LDS) + s_dep(global) + bias
    float b0 = edge_b[0];
    const float* scol = s_dep + (size_t)bz * S_DIM;
    float* Cf = out + (size_t)bz * S_DIM * S_DIM;
    int rloc0 = wr * 64;
    int col0  = tile_n + wc * 32;
    #pragma unroll
    for (int mt = 0; mt < 4; ++mt)
        #pragma unroll
        for (int r = 0; r < 4; ++r) {
            int rloc = rloc0 + mt * 16 + quad * 4 + r;
            int row  = tile_m + rloc;
            float sh = smrow[rloc] + b0;
            #pragma unroll
            for (int nt = 0; nt < 2; ++nt) {
                int col = col0 + nt * 16 + l16;
                __builtin_nontemporal_store(acc[mt][nt][r] + sh + scol[col],
                                            &Cf[(size_t)row * S_DIM + col]);
            }
        }
}

// ---------------------------------------------------------------------------
extern "C" void kernel_launch(void* const* d_in, const int* in_sizes, int n_in,
                              void* d_out, int out_size, void* d_ws, size_t ws_size,
                              hipStream_t stream) {
    const float* head   = (const float*)d_in[0];
    const float* dep    = (const float*)d_in[1];
    const float* edge_U = (const float*)d_in[2];
    const float* edge_W = (const float*)d_in[3];
    const float* edge_b = (const float*)d_in[4];
    float* out = (float*)d_out;

    char* ws = (char*)d_ws;
    const size_t nBSD = (size_t)B_DIM * S_DIM * D_DIM;

    bf16*  tmpD  = (bf16*)ws;  ws += nBSD * sizeof(bf16);
    float* s_dep = (float*)ws; ws += (size_t)B_DIM * S_DIM * sizeof(float);

    // K1: tmpD = dep @ U^T(row-major)  + fused s_dep projection
    gemm1_kernel<<<dim3(D_DIM / 128, (B_DIM * S_DIM) / 128, 1), 512, 0, stream>>>(
        dep, edge_U, edge_W, tmpD, s_dep);

    // K2: out = head @ tmpD^T + s_head(in-kernel) + s_dep + bias
    gemm2_kernel<<<dim3(S_DIM / 128, S_DIM / 128, B_DIM), 512, 0, stream>>>(
        head, tmpD, edge_W, s_dep, edge_b, out);
}